// Round 4
// baseline (631.955 us; speedup 1.0000x reference)
//
#include <hip/hip_runtime.h>

#define DD 128
#define K2 256     // concatenated K: [msg | ego*msg]
#define NBMAX 1024 // max bucket count (N/128)
#define COLMASK 0x01FFFFFF
#define SCAP 4096  // sortbkt LDS out-buffer capacity (entries)

typedef short short8 __attribute__((ext_vector_type(8)));
typedef float f32x4  __attribute__((ext_vector_type(4)));
typedef unsigned int uint4v __attribute__((ext_vector_type(4)));

static inline size_t align256(size_t x){ return (x + 255) & ~(size_t)255; }

__device__ __forceinline__ unsigned short f2bf(float x){
  unsigned int u = __builtin_bit_cast(unsigned int, x);
  u += 0x7fff + ((u >> 16) & 1);          // RNE fp32 -> bf16
  return (unsigned short)(u >> 16);
}
__device__ __forceinline__ float bf2f(unsigned short h){
  unsigned int u = ((unsigned int)h) << 16;
  return __builtin_bit_cast(float, u);
}

__device__ __forceinline__ short8 prod8(short8 mv, short8 ev){
  short8 r;
#pragma unroll
  for (int u = 0; u < 8; u++){
    float p = bf2f((unsigned short)mv[u]) * bf2f((unsigned short)ev[u]);
    r[u] = (short)f2bf(p);
  }
  return r;
}

// nontemporal int2 load (edge stream is read exactly once -> keep L2 for features)
__device__ __forceinline__ int2 ntload_i2(const int2* p){
  unsigned long long v = __builtin_nontemporal_load((const unsigned long long*)p);
  return make_int2((int)(unsigned int)v, (int)(unsigned int)(v >> 32));
}

__device__ __forceinline__ void acc8(float* a, uint4v v, float w){
#pragma unroll
  for (int j = 0; j < 4; j++){
    unsigned int u = v[j];
    a[2*j]   = fmaf(w, bf2f((unsigned short)u), a[2*j]);
    a[2*j+1] = fmaf(w, bf2f((unsigned short)(u >> 16)), a[2*j+1]);
  }
}

// ---------------- bucket histogram: LDS hist -> few global atomics ----------------
__global__ __launch_bounds__(256) void bucket_hist_kernel(
    const int* __restrict__ ei, int E, int* __restrict__ bcnt, int NB){
  __shared__ int lh[NBMAX];
  int t = threadIdx.x;
  int base = blockIdx.x * 8192;
  for (int j = t; j < NB; j += 256) lh[j] = 0;
  __syncthreads();
#pragma unroll
  for (int i = 0; i < 32; i++){
    int e = base + i*256 + t;
    if (e < E) atomicAdd(&lh[ei[e] >> 7], 1);
  }
  __syncthreads();
  for (int j = t; j < NB; j += 256){
    int c = lh[j];
    if (c) atomicAdd(&bcnt[j], c);
  }
}

// ---------------- bucket scan: bbase = excl scan(bcnt); bcur = bbase ----------------
__global__ __launch_bounds__(1024) void bucket_scan_kernel(
    const int* __restrict__ bcnt, int* __restrict__ bbase, int* __restrict__ bcur, int NB){
  __shared__ int a[NBMAX], btmp[NBMAX];
  int t = threadIdx.x;
  a[t] = (t < NB) ? bcnt[t] : 0;
  __syncthreads();
  int* src = a; int* dst = btmp;
  for (int o = 1; o < 1024; o <<= 1){
    int val = src[t];
    if (t >= o) val += src[t - o];
    dst[t] = val;
    __syncthreads();
    int* tm = src; src = dst; dst = tm;
  }
  int excl = (t == 0) ? 0 : src[t-1];
  if (t < NB){ bbase[t] = excl; bcur[t] = excl; }
}

// ---------------- binned fill, phase A ----------------
__global__ __launch_bounds__(256) void fill_binned_kernel(
    const int* __restrict__ ei, const float* __restrict__ ew, int E,
    int* __restrict__ bcur, int2* __restrict__ csre, int NB){
  __shared__ int lhist[NBMAX];
  __shared__ int lbase[NBMAX];
  int t = threadIdx.x;
  int base = blockIdx.x * 4096;
  for (int j = t; j < NB; j += 256) lhist[j] = 0;
  __syncthreads();
  int rows[16];
#pragma unroll
  for (int i = 0; i < 16; i++){
    int e = base + i*256 + t;
    int r = (e < E) ? ei[e] : -1;
    rows[i] = r;
    if (r >= 0) atomicAdd(&lhist[r >> 7], 1);
  }
  __syncthreads();
  for (int j = t; j < NB; j += 256){
    int c = lhist[j];
    lbase[j] = c ? atomicAdd(&bcur[j], c) : 0;
    lhist[j] = 0;
  }
  __syncthreads();
#pragma unroll
  for (int i = 0; i < 16; i++){
    int e = base + i*256 + t;
    int r = rows[i];
    if (r >= 0){
      int b = r >> 7;
      int pos = lbase[b] + atomicAdd(&lhist[b], 1);
      int col = ei[E + e];
      float w = ew[e];
      csre[pos] = make_int2(((r & 127) << 25) | col, __float_as_int(w));
    }
  }
}

// ---------------- per-bucket row degrees + padded bucket sums ----------------
__global__ __launch_bounds__(256) void bucket_rowdeg_kernel(
    const int* __restrict__ bbase, const int* __restrict__ bcur,
    const int2* __restrict__ csre, int* __restrict__ deg, int* __restrict__ psum, int N){
  __shared__ int lc[128];
  __shared__ int red[128];
  int b = blockIdx.x, t = threadIdx.x;
  if (t < 128) lc[t] = 0;
  __syncthreads();
  int beg = bbase[b], end = bcur[b];
  for (int i = beg + t; i < end; i += 256)
    atomicAdd(&lc[((unsigned int)csre[i].x) >> 25], 1);
  __syncthreads();
  int gr = b*128 + t;
  int d = 0;
  if (t < 128 && gr < N){ d = lc[t]; deg[gr] = d; }
  if (t < 128) red[t] = (d + 7) & ~7;
  __syncthreads();
  for (int o = 64; o > 0; o >>= 1){
    if (t < o) red[t] += red[t+o];
    __syncthreads();
  }
  if (t == 0) psum[b] = red[0];
}

// ---------------- padded-bucket scan ----------------
__global__ __launch_bounds__(1024) void pscan_kernel(
    const int* __restrict__ psum, int* __restrict__ pbase, int* __restrict__ rowptrN, int NB){
  __shared__ int a[NBMAX], btmp[NBMAX];
  int t = threadIdx.x;
  a[t] = (t < NB) ? psum[t] : 0;
  __syncthreads();
  int* src = a; int* dst = btmp;
  for (int o = 1; o < 1024; o <<= 1){
    int val = src[t];
    if (t >= o) val += src[t - o];
    dst[t] = val;
    __syncthreads();
    int* tm = src; src = dst; dst = tm;
  }
  int excl = (t == 0) ? 0 : src[t-1];
  if (t < NB) pbase[t] = excl;
  if (t == NB-1) *rowptrN = excl + psum[t];
}

// ---------------- phase B: local rowptr derivation + LDS-staged rank/pad -> coalesced ------
// Pad entries are (col=0, w=0): w=0 contributes nothing, and ALL pad loads hit the
// same 256B line (node 0's row) -> L2-broadcast instead of random HBM fetch.
__global__ __launch_bounds__(256) void sortbkt_kernel(
    const int* __restrict__ pbase, const int* __restrict__ bbase, const int* __restrict__ bcur,
    const int* __restrict__ deg, const int2* __restrict__ csre, int2* __restrict__ csre2,
    int* __restrict__ rowptr, int N){
  __shared__ int2 obuf[SCAP];
  __shared__ int lrp[129];
  __shared__ int lcur[128];
  __shared__ int sa[128], sb[128];
  int b = blockIdx.x;
  int t = threadIdx.x;
  int r0 = b*128;
  int gr = r0 + t;
  int d = (t < 128 && gr < N) ? deg[gr] : 0;
  if (t < 128){ sa[t] = (d + 7) & ~7; lcur[t] = 0; }
  __syncthreads();
  int* s0 = sa; int* s1 = sb;
  for (int o = 1; o < 128; o <<= 1){
    if (t < 128){
      int v = s0[t];
      if (t >= o) v += s0[t - o];
      s1[t] = v;
    }
    __syncthreads();
    int* tm = s0; s0 = s1; s1 = tm;
  }
  int pb = pbase[b];
  if (t < 128){
    int excl = t ? s0[t-1] : 0;
    lrp[t] = pb + excl;
    if (gr < N) rowptr[gr] = pb + excl;
    if (t == 127) lrp[128] = pb + s0[127];
  }
  __syncthreads();

  int gb = lrp[0];
  int outLen = lrp[128] - gb;
  int beg = bbase[b], bend = bcur[b];
  const int2 pad = make_int2(0, 0);   // col 0, w 0 -> L2-hot no-op edge

  if (outLen <= SCAP){
    for (int i = beg + t; i < bend; i += 256){
      int2 e = csre[i];
      int rl = ((unsigned int)e.x) >> 25;
      int pos = lrp[rl] - gb + atomicAdd(&lcur[rl], 1);
      obuf[pos] = e;
    }
    if (t < 128 && gr < N){
      int pbg = lrp[t] - gb + d, pe = lrp[t+1] - gb;
      for (int i = pbg; i < pe; i++) obuf[i] = pad;
    }
    __syncthreads();
    for (int i = t; i < outLen; i += 256) csre2[gb + i] = obuf[i];
  } else {
    for (int i = beg + t; i < bend; i += 256){
      int2 e = csre[i];
      int rl = ((unsigned int)e.x) >> 25;
      int pos = lrp[rl] + atomicAdd(&lcur[rl], 1);
      csre2[pos] = e;
    }
    __syncthreads();
    if (t < 128 && gr < N){
      int pbeg = lrp[t] + lcur[t];
      int pend = lrp[t+1];
      for (int i = pbeg; i < pend; i++) csre2[i] = pad;
    }
  }
}

// ---------------- fused: weight pack + emb->bf16 stage0 (interleaved feat4) ----------------
__global__ void pack_cvt_kernel(const float* __restrict__ gcw, const float* __restrict__ biw,
                                unsigned short* __restrict__ wb, int LYR,
                                const float* __restrict__ emb, unsigned int* __restrict__ feat4u,
                                int n2, int fsU){
  int i = blockIdx.x*blockDim.x + threadIdx.x;
  int wtotal = LYR*DD*K2;
  if (i < wtotal){
    int l = i / (DD*K2);
    int r = i - l*(DD*K2);
    int n = r >> 8;
    int k = r & (K2-1);
    float v = (k < DD) ? gcw[(size_t)l*DD*DD + n*DD + k]
                       : biw[(size_t)l*DD*DD + n*DD + (k - DD)];
    wb[i] = f2bf(v);
    return;
  }
  int j = i - wtotal;
  if (j < n2){
    float2 v = *(const float2*)(emb + (size_t)j*2);
    int n = j >> 6, c = j & 63;
    feat4u[(size_t)n*fsU + c] = (unsigned int)f2bf(v.x) | ((unsigned int)f2bf(v.y) << 16);
  }
}

// ---------------- fused layer: gather (16 rows/wave) + MFMA transform, one kernel -------
// Eliminates the msgh HBM round-trip (25.6MB write + read per layer) and one dispatch
// per layer. Per wave: gather 16 contiguous rows (same 4-group dwordx4 pattern as the
// standalone gather -- memory-pattern-bound at ~3.55 TB/s, proven ceiling), park each
// reduced msg row in a 4KB wave-private LDS scratch (XOR swizzle ((row&7)<<3) in
// ushort units breaks the stride-256B bank conflict on the fragment read; residual
// 2-way is free), then transpose-read A-fragments and run the MFMA loop streaming
// weights from L2. No barriers (wave-local LDS). Weight-stream latency hides under
// other waves still in their gather phase (phase-staggered naturally).
__global__ __launch_bounds__(256) void layer_fused_kernel(
    const int* __restrict__ rowptr, const int2* __restrict__ csre,
    const unsigned short* __restrict__ feat, int fs,
    const unsigned short* __restrict__ wb, const float* __restrict__ gcb,
    const float* __restrict__ bib, unsigned short* __restrict__ ego_out,
    float* __restrict__ nscale, int N){   // nscale: stride-3 base for this layer
  __shared__ unsigned short lmsg[4*2048];  // 4 waves x 16 rows x 128 bf16 = 16KB
  int t = threadIdx.x;
  int wave = t >> 6, lane = t & 63;
  int g = lane >> 4, fl = lane & 15;
  int wr0 = blockIdx.x * 64 + wave * 16;
  unsigned short* ms = lmsg + wave*2048;

  // one coalesced rowptr read for all 16 rows; per-row bounds via readlane/shfl
  int ridx = wr0 + fl; if (ridx > N-1) ridx = N-1;
  int rp0 = rowptr[ridx], rp1 = rowptr[ridx+1];

  const unsigned short* fbase = feat + fl*8;
  for (int r = 0; r < 16; r++){
    int beg = __shfl(rp0, r, 64);
    int end = __shfl(rp1, r, 64);
    float a[8];
#pragma unroll
    for (int i = 0; i < 8; i++) a[i] = 0.f;
    const int2* ep = csre + beg + g;
    int k = beg;
    for (; k + 16 <= end; k += 16){      // 16 edges/iter, 4 per group
      int2 e0 = ntload_i2(ep);
      int2 e1 = ntload_i2(ep + 4);
      int2 e2 = ntload_i2(ep + 8);
      int2 e3 = ntload_i2(ep + 12);
      uint4v v0 = *(const uint4v*)(fbase + (size_t)(e0.x & COLMASK)*fs);
      uint4v v1 = *(const uint4v*)(fbase + (size_t)(e1.x & COLMASK)*fs);
      uint4v v2 = *(const uint4v*)(fbase + (size_t)(e2.x & COLMASK)*fs);
      uint4v v3 = *(const uint4v*)(fbase + (size_t)(e3.x & COLMASK)*fs);
      acc8(a, v0, __int_as_float(e0.y));
      acc8(a, v1, __int_as_float(e1.y));
      acc8(a, v2, __int_as_float(e2.y));
      acc8(a, v3, __int_as_float(e3.y));
      ep += 16;
    }
    for (; k < end; k += 8){             // at most one trailing 8-batch (rows padded x8)
      int2 e0 = ntload_i2(ep);
      int2 e1 = ntload_i2(ep + 4);
      uint4v v0 = *(const uint4v*)(fbase + (size_t)(e0.x & COLMASK)*fs);
      uint4v v1 = *(const uint4v*)(fbase + (size_t)(e1.x & COLMASK)*fs);
      acc8(a, v0, __int_as_float(e0.y));
      acc8(a, v1, __int_as_float(e1.y));
      ep += 8;
    }
#pragma unroll
    for (int i = 0; i < 8; i++){
      a[i] += __shfl_xor(a[i], 16, 64);
      a[i] += __shfl_xor(a[i], 32, 64);
    }
    if (g == 0){
      uint4v o;
      o.x = (unsigned int)f2bf(a[0]) | ((unsigned int)f2bf(a[1]) << 16);
      o.y = (unsigned int)f2bf(a[2]) | ((unsigned int)f2bf(a[3]) << 16);
      o.z = (unsigned int)f2bf(a[4]) | ((unsigned int)f2bf(a[5]) << 16);
      o.w = (unsigned int)f2bf(a[6]) | ((unsigned int)f2bf(a[7]) << 16);
      // swizzled: ushort index r*128 + ((fl*8) ^ ((r&7)<<3))
      *(uint4v*)&ms[r*128 + ((fl*8) ^ ((r&7)<<3))] = o;
    }
  }

  // ---- transform phase (wave-local LDS; no barrier needed) ----
  int m = lane & 15, q = lane >> 4;
  short8 mv[4];
#pragma unroll
  for (int cc = 0; cc < 4; cc++)
    mv[cc] = *(const short8*)&ms[m*128 + ((cc*32 + q*8) ^ ((m&7)<<3))];

  int row0 = wr0 + m;
  int cr0 = row0 < N ? row0 : N-1;
  const unsigned short* erow0 = feat + (size_t)cr0*fs;
  short8 ev[4], pv[4];
#pragma unroll
  for (int cc = 0; cc < 4; cc++) ev[cc] = *(const short8*)(erow0 + cc*32 + q*8);
#pragma unroll
  for (int cc = 0; cc < 4; cc++) pv[cc] = prod8(mv[cc], ev[cc]);

  float bias[8];
#pragma unroll
  for (int ct = 0; ct < 8; ct++) bias[ct] = gcb[ct*16 + m] + bib[ct*16 + m];

  const unsigned short* wrow = wb + (size_t)m*K2;
  f32x4 acc[8];
#pragma unroll
  for (int ct = 0; ct < 8; ct++) acc[ct] = (f32x4)0.f;

#pragma unroll
  for (int cc = 0; cc < 4; cc++){
    int c = cc*32 + q*8;
#pragma unroll
    for (int ct = 0; ct < 8; ct++){
      short8 bm = *(const short8*)(wrow + (size_t)ct*16*K2 + c);
      short8 bp = *(const short8*)(wrow + (size_t)ct*16*K2 + DD + c);
      acc[ct] = __builtin_amdgcn_mfma_f32_16x16x32_bf16(mv[cc], bm, acc[ct], 0, 0, 0);
      acc[ct] = __builtin_amdgcn_mfma_f32_16x16x32_bf16(pv[cc], bp, acc[ct], 0, 0, 0);
    }
  }

#pragma unroll
  for (int reg = 0; reg < 4; reg++){
    int gr = wr0 + q*4 + reg;
    float rs = 0.f;
#pragma unroll
    for (int ct = 0; ct < 8; ct++){
      float x = acc[ct][reg] + bias[ct];
      x = (x > 0.f) ? x : 0.2f*x;
      rs += x*x;
      if (gr < N) ego_out[(size_t)gr*fs + ct*16 + m] = f2bf(x);
    }
#pragma unroll
    for (int o = 1; o < 16; o <<= 1) rs += __shfl_xor(rs, o, 16);
    if (m == 0 && gr < N)
      nscale[(size_t)gr*3] = 1.0f / fmaxf(sqrtf(rs), 1e-12f);
  }
}

// ---------------- score: dwordx4 per lane -> one wave-load covers a full 1KB row ----------
__global__ void score_all_kernel(const int* __restrict__ eli, int Q,
                                 const unsigned int* __restrict__ feat4u, int fsU,
                                 const float* __restrict__ nsall,  // [n][3]
                                 float* __restrict__ out){
  int wid = (int)(((size_t)blockIdx.x*blockDim.x + threadIdx.x) >> 6);
  int lane = threadIdx.x & 63;
  if (wid >= Q) return;
  int s = eli[wid];
  int d = eli[Q + wid];
  int g = lane >> 4;
  uint4v a = *(const uint4v*)(feat4u + (size_t)s*fsU + lane*4);
  uint4v b = *(const uint4v*)(feat4u + (size_t)d*fsU + lane*4);
  int so = g ? (g - 1) : 0;
  float ls = nsall[(size_t)s*3 + so];
  float ld = nsall[(size_t)d*3 + so];
  float p = 0.f;
#pragma unroll
  for (int j = 0; j < 4; j++){
    p += bf2f((unsigned short)a[j]) * bf2f((unsigned short)b[j]);
    p += bf2f((unsigned short)(a[j] >> 16)) * bf2f((unsigned short)(b[j] >> 16));
  }
  if (g) p *= ls * ld;                 // stage 0 (raw emb) unscaled
  for (int o = 32; o > 0; o >>= 1) p += __shfl_xor(p, o, 64);
  if (lane == 0) out[wid] = p;
}

extern "C" void kernel_launch(void* const* d_in, const int* in_sizes, int n_in,
                              void* d_out, int out_size, void* d_ws, size_t ws_size,
                              hipStream_t stream){
  const int*   edge_index = (const int*)d_in[0];
  const int*   eli        = (const int*)d_in[1];
  const float* ew         = (const float*)d_in[2];
  const float* emb        = (const float*)d_in[3];
  const float* gcw        = (const float*)d_in[4];
  const float* gcb        = (const float*)d_in[5];
  const float* biw        = (const float*)d_in[6];
  const float* bib        = (const float*)d_in[7];
  const int E   = in_sizes[2];
  const int Q   = in_sizes[1] / 2;
  const int N   = in_sizes[3] / DD;
  const int LYR = in_sizes[4] / (DD*DD);
  float* out = (float*)d_out;

  const int FS  = (LYR + 1) * DD;   // interleaved per-node feature stride (512 for LYR=3)
  const int FSU = FS / 2;

  char* base = (char*)d_ws;
  size_t off = 0;
  auto carve = [&](size_t bytes)->char*{
    char* r = base + off;
    off = align256(off + bytes);
    return r;
  };

  unsigned short* feat4  = (unsigned short*) carve((size_t)N*FS*sizeof(unsigned short));
  // csre (setup phase A temp) keeps its carve; msgh is gone (fused kernel)
  size_t csreB_ = (size_t)E*sizeof(int2);
  int2*           csre   = (int2*)           carve(csreB_);
  unsigned short* wb     = (unsigned short*) carve((size_t)LYR*DD*K2*sizeof(unsigned short));
  float*          nsall  = (float*)          carve((size_t)3*N*sizeof(float));
  int*            rowptr = (int*)            carve((size_t)(N+1)*sizeof(int));
  int*            deg    = (int*)            carve((size_t)N*sizeof(int));
  int*            bcnt   = (int*)            carve((size_t)NBMAX*sizeof(int));
  int*            bbase  = (int*)            carve((size_t)NBMAX*sizeof(int));
  int*            bcur   = (int*)            carve((size_t)NBMAX*sizeof(int));
  int*            psum   = (int*)            carve((size_t)NBMAX*sizeof(int));
  int*            pbase  = (int*)            carve((size_t)NBMAX*sizeof(int));
  int2*           csre2  = (int2*)           carve(((size_t)E + 7*(size_t)N + 8)*sizeof(int2));
  (void)n_in; (void)out_size; (void)ws_size;

  const int NB = (N + 127)/128;

  // setup: hist -> bucket scan -> raw fill -> rowdeg(+psum) -> pscan -> sort(+rowptr) -> pack+cvt
  hipMemsetAsync(bcnt, 0, (size_t)NB*sizeof(int), stream);
  bucket_hist_kernel<<<(E + 8191)/8192, 256, 0, stream>>>(edge_index, E, bcnt, NB);
  bucket_scan_kernel<<<1, 1024, 0, stream>>>(bcnt, bbase, bcur, NB);
  fill_binned_kernel<<<(E + 4095)/4096, 256, 0, stream>>>(edge_index, ew, E, bcur, csre, NB);
  bucket_rowdeg_kernel<<<NB, 256, 0, stream>>>(bbase, bcur, csre, deg, psum, N);
  pscan_kernel<<<1, 1024, 0, stream>>>(psum, pbase, rowptr + N, NB);
  sortbkt_kernel<<<NB, 256, 0, stream>>>(pbase, bbase, bcur, deg, csre, csre2, rowptr, N);
  {
    int total = LYR*DD*K2 + N*DD/2;
    pack_cvt_kernel<<<(total + 255)/256, 256, 0, stream>>>(
        gcw, biw, wb, LYR, emb, (unsigned int*)feat4, N*DD/2, FSU);
  }

  for (int l = 0; l < LYR; l++){
    layer_fused_kernel<<<(N + 63)/64, 256, 0, stream>>>(
        rowptr, csre2, feat4 + (size_t)l*DD, FS,
        wb + (size_t)l*DD*K2, gcb + (size_t)l*DD, bib + (size_t)l*DD,
        feat4 + (size_t)(l+1)*DD, nsall + l, N);
  }
  {
    int blocks = (int)(((size_t)Q*64 + 255)/256);
    score_all_kernel<<<blocks, 256, 0, stream>>>(eli, Q, (const unsigned int*)feat4, FSU,
                                                 nsall, out);
  }
}

// Round 5
// 485.752 us; speedup vs baseline: 1.3010x; 1.3010x over previous
//
#include <hip/hip_runtime.h>

#define DD 128
#define K2 256     // concatenated K: [msg | ego*msg]
#define NBMAX 1024 // max bucket count (N/128)
#define COLMASK 0x01FFFFFF
#define SCAP 4096  // sortbkt LDS out-buffer capacity (entries)

typedef short short8 __attribute__((ext_vector_type(8)));
typedef float f32x4  __attribute__((ext_vector_type(4)));
typedef unsigned int uint4v __attribute__((ext_vector_type(4)));

static inline size_t align256(size_t x){ return (x + 255) & ~(size_t)255; }

__device__ __forceinline__ unsigned short f2bf(float x){
  unsigned int u = __builtin_bit_cast(unsigned int, x);
  u += 0x7fff + ((u >> 16) & 1);          // RNE fp32 -> bf16
  return (unsigned short)(u >> 16);
}
__device__ __forceinline__ float bf2f(unsigned short h){
  unsigned int u = ((unsigned int)h) << 16;
  return __builtin_bit_cast(float, u);
}

__device__ __forceinline__ short8 prod8(short8 mv, short8 ev){
  short8 r;
#pragma unroll
  for (int u = 0; u < 8; u++){
    float p = bf2f((unsigned short)mv[u]) * bf2f((unsigned short)ev[u]);
    r[u] = (short)f2bf(p);
  }
  return r;
}

// nontemporal int2 load (edge stream is read exactly once -> keep L2 for features)
__device__ __forceinline__ int2 ntload_i2(const int2* p){
  unsigned long long v = __builtin_nontemporal_load((const unsigned long long*)p);
  return make_int2((int)(unsigned int)v, (int)(unsigned int)(v >> 32));
}

__device__ __forceinline__ void acc8(float* a, uint4v v, float w){
#pragma unroll
  for (int j = 0; j < 4; j++){
    unsigned int u = v[j];
    a[2*j]   = fmaf(w, bf2f((unsigned short)u), a[2*j]);
    a[2*j+1] = fmaf(w, bf2f((unsigned short)(u >> 16)), a[2*j+1]);
  }
}

// ---------------- bucket histogram: LDS hist -> few global atomics ----------------
__global__ __launch_bounds__(256) void bucket_hist_kernel(
    const int* __restrict__ ei, int E, int* __restrict__ bcnt, int NB){
  __shared__ int lh[NBMAX];
  int t = threadIdx.x;
  int base = blockIdx.x * 8192;
  for (int j = t; j < NB; j += 256) lh[j] = 0;
  __syncthreads();
#pragma unroll
  for (int i = 0; i < 32; i++){
    int e = base + i*256 + t;
    if (e < E) atomicAdd(&lh[ei[e] >> 7], 1);
  }
  __syncthreads();
  for (int j = t; j < NB; j += 256){
    int c = lh[j];
    if (c) atomicAdd(&bcnt[j], c);
  }
}

// ---------------- bucket scan: bbase = excl scan(bcnt); bcur = bbase ----------------
__global__ __launch_bounds__(1024) void bucket_scan_kernel(
    const int* __restrict__ bcnt, int* __restrict__ bbase, int* __restrict__ bcur, int NB){
  __shared__ int a[NBMAX], btmp[NBMAX];
  int t = threadIdx.x;
  a[t] = (t < NB) ? bcnt[t] : 0;
  __syncthreads();
  int* src = a; int* dst = btmp;
  for (int o = 1; o < 1024; o <<= 1){
    int val = src[t];
    if (t >= o) val += src[t - o];
    dst[t] = val;
    __syncthreads();
    int* tm = src; src = dst; dst = tm;
  }
  int excl = (t == 0) ? 0 : src[t-1];
  if (t < NB){ bbase[t] = excl; bcur[t] = excl; }
}

// ---------------- binned fill, phase A ----------------
__global__ __launch_bounds__(256) void fill_binned_kernel(
    const int* __restrict__ ei, const float* __restrict__ ew, int E,
    int* __restrict__ bcur, int2* __restrict__ csre, int NB){
  __shared__ int lhist[NBMAX];
  __shared__ int lbase[NBMAX];
  int t = threadIdx.x;
  int base = blockIdx.x * 4096;
  for (int j = t; j < NB; j += 256) lhist[j] = 0;
  __syncthreads();
  int rows[16];
#pragma unroll
  for (int i = 0; i < 16; i++){
    int e = base + i*256 + t;
    int r = (e < E) ? ei[e] : -1;
    rows[i] = r;
    if (r >= 0) atomicAdd(&lhist[r >> 7], 1);
  }
  __syncthreads();
  for (int j = t; j < NB; j += 256){
    int c = lhist[j];
    lbase[j] = c ? atomicAdd(&bcur[j], c) : 0;
    lhist[j] = 0;
  }
  __syncthreads();
#pragma unroll
  for (int i = 0; i < 16; i++){
    int e = base + i*256 + t;
    int r = rows[i];
    if (r >= 0){
      int b = r >> 7;
      int pos = lbase[b] + atomicAdd(&lhist[b], 1);
      int col = ei[E + e];
      float w = ew[e];
      csre[pos] = make_int2(((r & 127) << 25) | col, __float_as_int(w));
    }
  }
}

// ---------------- per-bucket row degrees + padded bucket sums ----------------
__global__ __launch_bounds__(256) void bucket_rowdeg_kernel(
    const int* __restrict__ bbase, const int* __restrict__ bcur,
    const int2* __restrict__ csre, int* __restrict__ deg, int* __restrict__ psum, int N){
  __shared__ int lc[128];
  __shared__ int red[128];
  int b = blockIdx.x, t = threadIdx.x;
  if (t < 128) lc[t] = 0;
  __syncthreads();
  int beg = bbase[b], end = bcur[b];
  for (int i = beg + t; i < end; i += 256)
    atomicAdd(&lc[((unsigned int)csre[i].x) >> 25], 1);
  __syncthreads();
  int gr = b*128 + t;
  int d = 0;
  if (t < 128 && gr < N){ d = lc[t]; deg[gr] = d; }
  if (t < 128) red[t] = (d + 7) & ~7;
  __syncthreads();
  for (int o = 64; o > 0; o >>= 1){
    if (t < o) red[t] += red[t+o];
    __syncthreads();
  }
  if (t == 0) psum[b] = red[0];
}

// ---------------- padded-bucket scan ----------------
__global__ __launch_bounds__(1024) void pscan_kernel(
    const int* __restrict__ psum, int* __restrict__ pbase, int* __restrict__ rowptrN, int NB){
  __shared__ int a[NBMAX], btmp[NBMAX];
  int t = threadIdx.x;
  a[t] = (t < NB) ? psum[t] : 0;
  __syncthreads();
  int* src = a; int* dst = btmp;
  for (int o = 1; o < 1024; o <<= 1){
    int val = src[t];
    if (t >= o) val += src[t - o];
    dst[t] = val;
    __syncthreads();
    int* tm = src; src = dst; dst = tm;
  }
  int excl = (t == 0) ? 0 : src[t-1];
  if (t < NB) pbase[t] = excl;
  if (t == NB-1) *rowptrN = excl + psum[t];
}

// ---------------- phase B: local rowptr derivation + LDS-staged rank/pad -> coalesced ------
// Pad entries are (col=0, w=0): w=0 contributes nothing, and ALL pad loads hit the
// same 256B line (node 0's row) -> L2-broadcast instead of random HBM fetch.
__global__ __launch_bounds__(256) void sortbkt_kernel(
    const int* __restrict__ pbase, const int* __restrict__ bbase, const int* __restrict__ bcur,
    const int* __restrict__ deg, const int2* __restrict__ csre, int2* __restrict__ csre2,
    int* __restrict__ rowptr, int N){
  __shared__ int2 obuf[SCAP];
  __shared__ int lrp[129];
  __shared__ int lcur[128];
  __shared__ int sa[128], sb[128];
  int b = blockIdx.x;
  int t = threadIdx.x;
  int r0 = b*128;
  int gr = r0 + t;
  int d = (t < 128 && gr < N) ? deg[gr] : 0;
  if (t < 128){ sa[t] = (d + 7) & ~7; lcur[t] = 0; }
  __syncthreads();
  int* s0 = sa; int* s1 = sb;
  for (int o = 1; o < 128; o <<= 1){
    if (t < 128){
      int v = s0[t];
      if (t >= o) v += s0[t - o];
      s1[t] = v;
    }
    __syncthreads();
    int* tm = s0; s0 = s1; s1 = tm;
  }
  int pb = pbase[b];
  if (t < 128){
    int excl = t ? s0[t-1] : 0;
    lrp[t] = pb + excl;
    if (gr < N) rowptr[gr] = pb + excl;
    if (t == 127) lrp[128] = pb + s0[127];
  }
  __syncthreads();

  int gb = lrp[0];
  int outLen = lrp[128] - gb;
  int beg = bbase[b], bend = bcur[b];
  const int2 pad = make_int2(0, 0);   // col 0, w 0 -> L2-hot no-op edge

  if (outLen <= SCAP){
    for (int i = beg + t; i < bend; i += 256){
      int2 e = csre[i];
      int rl = ((unsigned int)e.x) >> 25;
      int pos = lrp[rl] - gb + atomicAdd(&lcur[rl], 1);
      obuf[pos] = e;
    }
    if (t < 128 && gr < N){
      int pbg = lrp[t] - gb + d, pe = lrp[t+1] - gb;
      for (int i = pbg; i < pe; i++) obuf[i] = pad;
    }
    __syncthreads();
    for (int i = t; i < outLen; i += 256) csre2[gb + i] = obuf[i];
  } else {
    for (int i = beg + t; i < bend; i += 256){
      int2 e = csre[i];
      int rl = ((unsigned int)e.x) >> 25;
      int pos = lrp[rl] + atomicAdd(&lcur[rl], 1);
      csre2[pos] = e;
    }
    __syncthreads();
    if (t < 128 && gr < N){
      int pbeg = lrp[t] + lcur[t];
      int pend = lrp[t+1];
      for (int i = pbeg; i < pend; i++) csre2[i] = pad;
    }
  }
}

// ---------------- fused: weight pack + emb->bf16 stage0 (interleaved feat4) ----------------
__global__ void pack_cvt_kernel(const float* __restrict__ gcw, const float* __restrict__ biw,
                                unsigned short* __restrict__ wb, int LYR,
                                const float* __restrict__ emb, unsigned int* __restrict__ feat4u,
                                int n2, int fsU){
  int i = blockIdx.x*blockDim.x + threadIdx.x;
  int wtotal = LYR*DD*K2;
  if (i < wtotal){
    int l = i / (DD*K2);
    int r = i - l*(DD*K2);
    int n = r >> 8;
    int k = r & (K2-1);
    float v = (k < DD) ? gcw[(size_t)l*DD*DD + n*DD + k]
                       : biw[(size_t)l*DD*DD + n*DD + (k - DD)];
    wb[i] = f2bf(v);
    return;
  }
  int j = i - wtotal;
  if (j < n2){
    float2 v = *(const float2*)(emb + (size_t)j*2);
    int n = j >> 6, c = j & 63;
    feat4u[(size_t)n*fsU + c] = (unsigned int)f2bf(v.x) | ((unsigned int)f2bf(v.y) << 16);
  }
}

// ---------------- gather (tail-free, rows padded x8): 16-lane groups, dwordx4 loads -------
// Wave = one dst row (25000 blocks -> max TLP; random-row BW needs occupancy x
// outstanding-loads, proven in r4's fused failure). One vmem instr covers 4 edges.
// Edge stream AND msg store nontemporal (r2 showed cached msg stores evict the
// feature table: +43us).
__global__ void gather_kernel(const int* __restrict__ rowptr, const int2* __restrict__ csre,
                              const unsigned short* __restrict__ feat, int fs,
                              unsigned int* __restrict__ msgh, int N){
  int wid = (int)(((size_t)blockIdx.x*blockDim.x + threadIdx.x) >> 6);
  int lane = threadIdx.x & 63;
  if (wid >= N) return;
  int g  = lane >> 4;
  int fl = lane & 15;
  int beg = rowptr[wid], end = rowptr[wid+1];
  const unsigned short* fbase = feat + fl*8;
  float a[8];
#pragma unroll
  for (int i = 0; i < 8; i++) a[i] = 0.f;

  const int2* ep = csre + beg + g;
  int k = beg;
  for (; k + 16 <= end; k += 16){      // 16 edges/iter, 4 per group
    int2 e0 = ntload_i2(ep);
    int2 e1 = ntload_i2(ep + 4);
    int2 e2 = ntload_i2(ep + 8);
    int2 e3 = ntload_i2(ep + 12);
    uint4v v0 = *(const uint4v*)(fbase + (size_t)(e0.x & COLMASK)*fs);
    uint4v v1 = *(const uint4v*)(fbase + (size_t)(e1.x & COLMASK)*fs);
    uint4v v2 = *(const uint4v*)(fbase + (size_t)(e2.x & COLMASK)*fs);
    uint4v v3 = *(const uint4v*)(fbase + (size_t)(e3.x & COLMASK)*fs);
    acc8(a, v0, __int_as_float(e0.y));
    acc8(a, v1, __int_as_float(e1.y));
    acc8(a, v2, __int_as_float(e2.y));
    acc8(a, v3, __int_as_float(e3.y));
    ep += 16;
  }
  for (; k < end; k += 8){             // at most one trailing 8-batch (rows padded x8)
    int2 e0 = ntload_i2(ep);
    int2 e1 = ntload_i2(ep + 4);
    uint4v v0 = *(const uint4v*)(fbase + (size_t)(e0.x & COLMASK)*fs);
    uint4v v1 = *(const uint4v*)(fbase + (size_t)(e1.x & COLMASK)*fs);
    acc8(a, v0, __int_as_float(e0.y));
    acc8(a, v1, __int_as_float(e1.y));
    ep += 8;
  }

  // combine the 4 edge substreams (groups) per feature slot
#pragma unroll
  for (int i = 0; i < 8; i++){
    a[i] += __shfl_xor(a[i], 16, 64);
    a[i] += __shfl_xor(a[i], 32, 64);
  }
  if (g == 0){
    uint4v o;
    o.x = (unsigned int)f2bf(a[0]) | ((unsigned int)f2bf(a[1]) << 16);
    o.y = (unsigned int)f2bf(a[2]) | ((unsigned int)f2bf(a[3]) << 16);
    o.z = (unsigned int)f2bf(a[4]) | ((unsigned int)f2bf(a[5]) << 16);
    o.w = (unsigned int)f2bf(a[6]) | ((unsigned int)f2bf(a[7]) << 16);
    __builtin_nontemporal_store(o, (uint4v*)(msgh + (size_t)wid*(DD/2) + fl*4));
  }
}

// ---------------- transform (bf16 MFMA, K=256): LDS-staged weights, 8-wave blocks -----
// r3 used 256-thr blocks: 64KB LDS stage capped residency at 2 blocks/CU = 8 waves/CU,
// and 782 blocks restaged 50MB total. Now 512-thr (8-wave) blocks share one staging:
// 16 waves/CU resident, 391 blocks = 25MB staging, same 3128 waves / same per-wave code.
// XOR swizzle ((row&7)<<4 on byte offset) on both write and read breaks the 512B-row
// bank conflict.
__global__ __launch_bounds__(512) void transform_mfma_kernel(
    const unsigned short* __restrict__ ego_in, const unsigned short* __restrict__ msgh,
    int fs, const unsigned short* __restrict__ wb, const float* __restrict__ gcb,
    const float* __restrict__ bib, unsigned short* __restrict__ ego_out,
    float* __restrict__ nscale, int N){   // nscale: stride-3 base for this layer
  __shared__ unsigned short lw[DD*K2];    // 64KB
  int t = threadIdx.x;
  int wave = t >> 6, lane = t & 63;
  int m = lane & 15, q = lane >> 4;
  int wr0 = blockIdx.x * 256 + wave * 32;

  int row0 = wr0 + m, row1 = wr0 + 16 + m;
  int cr0 = row0 < N ? row0 : N-1;
  int cr1 = row1 < N ? row1 : N-1;
  const unsigned short* mrow0 = msgh   + (size_t)cr0*DD;
  const unsigned short* mrow1 = msgh   + (size_t)cr1*DD;
  const unsigned short* erow0 = ego_in + (size_t)cr0*fs;
  const unsigned short* erow1 = ego_in + (size_t)cr1*fs;

  // hoist feature loads (issued before staging loop -> latency overlaps staging)
  short8 mv0[4], ev0[4], mv1[4], ev1[4];
#pragma unroll
  for (int cc = 0; cc < 4; cc++){
    int c = cc*32 + q*8;
    mv0[cc] = *(const short8*)(mrow0 + c);
    ev0[cc] = *(const short8*)(erow0 + c);
    mv1[cc] = *(const short8*)(mrow1 + c);
    ev1[cc] = *(const short8*)(erow1 + c);
  }

  // stage weights -> LDS, 16B chunks, XOR swizzle on 16B slot within 128B window
  for (int idx = t; idx < DD*K2/8; idx += 512){
    int bo = idx*16;
    int swz = bo ^ (((bo >> 9) & 7) << 4);
    *(short8*)((char*)lw + swz) = *(const short8*)((const char*)wb + bo);
  }

  float bias[8];
#pragma unroll
  for (int ct = 0; ct < 8; ct++) bias[ct] = gcb[ct*16 + m] + bib[ct*16 + m];

  short8 pv0[4], pv1[4];
#pragma unroll
  for (int cc = 0; cc < 4; cc++){
    pv0[cc] = prod8(mv0[cc], ev0[cc]);
    pv1[cc] = prod8(mv1[cc], ev1[cc]);
  }

  f32x4 acc[8][2];
#pragma unroll
  for (int ct = 0; ct < 8; ct++){ acc[ct][0] = (f32x4)0.f; acc[ct][1] = (f32x4)0.f; }

  __syncthreads();

#pragma unroll
  for (int cc = 0; cc < 4; cc++){
    int cb = (cc*32 + q*8)*2;           // byte offset of k-chunk within a weight row
#pragma unroll
    for (int ct = 0; ct < 8; ct++){
      int wr = ct*16 + m;               // weight row = output col
      int rb = wr*512;
      int sw = ((wr & 7) << 4);
      short8 bm = *(const short8*)((const char*)lw + ((rb + cb) ^ sw));
      short8 bp = *(const short8*)((const char*)lw + ((rb + 256 + cb) ^ sw));
      acc[ct][0] = __builtin_amdgcn_mfma_f32_16x16x32_bf16(mv0[cc], bm, acc[ct][0], 0, 0, 0);
      acc[ct][1] = __builtin_amdgcn_mfma_f32_16x16x32_bf16(mv1[cc], bm, acc[ct][1], 0, 0, 0);
      acc[ct][0] = __builtin_amdgcn_mfma_f32_16x16x32_bf16(pv0[cc], bp, acc[ct][0], 0, 0, 0);
      acc[ct][1] = __builtin_amdgcn_mfma_f32_16x16x32_bf16(pv1[cc], bp, acc[ct][1], 0, 0, 0);
    }
  }

#pragma unroll
  for (int rt = 0; rt < 2; rt++){
#pragma unroll
    for (int reg = 0; reg < 4; reg++){
      int gr = wr0 + rt*16 + q*4 + reg;
      float rs = 0.f;
#pragma unroll
      for (int ct = 0; ct < 8; ct++){
        float x = acc[ct][rt][reg] + bias[ct];
        x = (x > 0.f) ? x : 0.2f*x;
        rs += x*x;
        if (gr < N) ego_out[(size_t)gr*fs + ct*16 + m] = f2bf(x);
      }
#pragma unroll
      for (int o = 1; o < 16; o <<= 1) rs += __shfl_xor(rs, o, 16);
      if (m == 0 && gr < N)
        nscale[(size_t)gr*3] = 1.0f / fmaxf(sqrtf(rs), 1e-12f);
    }
  }
}

// ---------------- score: dwordx4 per lane -> one wave-load covers a full 1KB row ----------
__global__ void score_all_kernel(const int* __restrict__ eli, int Q,
                                 const unsigned int* __restrict__ feat4u, int fsU,
                                 const float* __restrict__ nsall,  // [n][3]
                                 float* __restrict__ out){
  int wid = (int)(((size_t)blockIdx.x*blockDim.x + threadIdx.x) >> 6);
  int lane = threadIdx.x & 63;
  if (wid >= Q) return;
  int s = eli[wid];
  int d = eli[Q + wid];
  int g = lane >> 4;
  uint4v a = *(const uint4v*)(feat4u + (size_t)s*fsU + lane*4);
  uint4v b = *(const uint4v*)(feat4u + (size_t)d*fsU + lane*4);
  int so = g ? (g - 1) : 0;
  float ls = nsall[(size_t)s*3 + so];
  float ld = nsall[(size_t)d*3 + so];
  float p = 0.f;
#pragma unroll
  for (int j = 0; j < 4; j++){
    p += bf2f((unsigned short)a[j]) * bf2f((unsigned short)b[j]);
    p += bf2f((unsigned short)(a[j] >> 16)) * bf2f((unsigned short)(b[j] >> 16));
  }
  if (g) p *= ls * ld;                 // stage 0 (raw emb) unscaled
  for (int o = 32; o > 0; o >>= 1) p += __shfl_xor(p, o, 64);
  if (lane == 0) out[wid] = p;
}

extern "C" void kernel_launch(void* const* d_in, const int* in_sizes, int n_in,
                              void* d_out, int out_size, void* d_ws, size_t ws_size,
                              hipStream_t stream){
  const int*   edge_index = (const int*)d_in[0];
  const int*   eli        = (const int*)d_in[1];
  const float* ew         = (const float*)d_in[2];
  const float* emb        = (const float*)d_in[3];
  const float* gcw        = (const float*)d_in[4];
  const float* gcb        = (const float*)d_in[5];
  const float* biw        = (const float*)d_in[6];
  const float* bib        = (const float*)d_in[7];
  const int E   = in_sizes[2];
  const int Q   = in_sizes[1] / 2;
  const int N   = in_sizes[3] / DD;
  const int LYR = in_sizes[4] / (DD*DD);
  float* out = (float*)d_out;

  const int FS  = (LYR + 1) * DD;   // interleaved per-node feature stride (512 for LYR=3)
  const int FSU = FS / 2;

  char* base = (char*)d_ws;
  size_t off = 0;
  auto carve = [&](size_t bytes)->char*{
    char* r = base + off;
    off = align256(off + bytes);
    return r;
  };

  unsigned short* feat4  = (unsigned short*) carve((size_t)N*FS*sizeof(unsigned short));
  // msgh (layer loop) aliases csre (setup phase A temp) -- disjoint lifetimes
  size_t msgB_ = (size_t)N*DD*sizeof(unsigned short);
  size_t csreB_ = (size_t)E*sizeof(int2);
  unsigned short* msgh   = (unsigned short*) carve(msgB_ > csreB_ ? msgB_ : csreB_);
  int2*           csre   = (int2*)msgh;
  unsigned short* wb     = (unsigned short*) carve((size_t)LYR*DD*K2*sizeof(unsigned short));
  float*          nsall  = (float*)          carve((size_t)3*N*sizeof(float));
  int*            rowptr = (int*)            carve((size_t)(N+1)*sizeof(int));
  int*            deg    = (int*)            carve((size_t)N*sizeof(int));
  int*            bcnt   = (int*)            carve((size_t)NBMAX*sizeof(int));
  int*            bbase  = (int*)            carve((size_t)NBMAX*sizeof(int));
  int*            bcur   = (int*)            carve((size_t)NBMAX*sizeof(int));
  int*            psum   = (int*)            carve((size_t)NBMAX*sizeof(int));
  int*            pbase  = (int*)            carve((size_t)NBMAX*sizeof(int));
  int2*           csre2  = (int2*)           carve(((size_t)E + 7*(size_t)N + 8)*sizeof(int2));
  (void)n_in; (void)out_size; (void)ws_size;

  const int NB = (N + 127)/128;

  // setup: hist -> bucket scan -> raw fill -> rowdeg(+psum) -> pscan -> sort(+rowptr) -> pack+cvt
  hipMemsetAsync(bcnt, 0, (size_t)NB*sizeof(int), stream);
  bucket_hist_kernel<<<(E + 8191)/8192, 256, 0, stream>>>(edge_index, E, bcnt, NB);
  bucket_scan_kernel<<<1, 1024, 0, stream>>>(bcnt, bbase, bcur, NB);
  fill_binned_kernel<<<(E + 4095)/4096, 256, 0, stream>>>(edge_index, ew, E, bcur, csre, NB);
  bucket_rowdeg_kernel<<<NB, 256, 0, stream>>>(bbase, bcur, csre, deg, psum, N);
  pscan_kernel<<<1, 1024, 0, stream>>>(psum, pbase, rowptr + N, NB);
  sortbkt_kernel<<<NB, 256, 0, stream>>>(pbase, bbase, bcur, deg, csre, csre2, rowptr, N);
  {
    int total = LYR*DD*K2 + N*DD/2;
    pack_cvt_kernel<<<(total + 255)/256, 256, 0, stream>>>(
        gcw, biw, wb, LYR, emb, (unsigned int*)feat4, N*DD/2, FSU);
  }

  for (int l = 0; l < LYR; l++){
    int blocks = (int)(((size_t)N*64 + 255)/256);
    gather_kernel<<<blocks, 256, 0, stream>>>(rowptr, csre2, feat4 + (size_t)l*DD, FS,
                                              (unsigned int*)msgh, N);
    transform_mfma_kernel<<<(N + 255)/256, 512, 0, stream>>>(
        feat4 + (size_t)l*DD, msgh, FS, wb + (size_t)l*DD*K2,
        gcb + (size_t)l*DD, bib + (size_t)l*DD,
        feat4 + (size_t)(l+1)*DD, nsall + l, N);
  }
  {
    int blocks = (int)(((size_t)Q*64 + 255)/256);
    score_all_kernel<<<blocks, 256, 0, stream>>>(eli, Q, (const unsigned int*)feat4, FSU,
                                                 nsall, out);
  }
}